// Round 3
// baseline (339.295 us; speedup 1.0000x reference)
//
#include <hip/hip_runtime.h>
#include <hip/hip_bf16.h>

#define TT 8
#define CC 128
#define DD 64
#define HWp 9216
#define PP 16
#define XB_STRIDE 152   // bf16 elems per pixel row (128 + 24 pad) = 304B, 16B-aligned
#define QKV_STRIDE 264  // bf16 elems per (t,p) row (256 + 8 pad) = 528B = 33x16B chunks (odd -> bank spread)
#define PS 4232         // per-t plane stride in shorts = 16*264 + 8 -> 8464B = 529 chunks (odd -> t-planes shift banks)

typedef __attribute__((ext_vector_type(8))) short short8;
typedef __attribute__((ext_vector_type(4))) short short4v;
typedef __attribute__((ext_vector_type(4))) float floatx4;
typedef __attribute__((ext_vector_type(2))) float float2v;

__device__ __forceinline__ short f2bf(float f) {
    __hip_bfloat16 h = __float2bfloat16(f);
    return __builtin_bit_cast(short, h);
}
__device__ __forceinline__ float bf2f(short s) {
    unsigned u = ((unsigned)(unsigned short)s) << 16;
    return __builtin_bit_cast(float, u);
}

// block = 512 threads = 8 waves; 2 blocks/CU (LDS-limited) = 16 waves/CU.
__global__ __launch_bounds__(512, 4) void ta_kernel(
    const float* __restrict__ x,
    const float* __restrict__ Wq, const float* __restrict__ bq,
    const float* __restrict__ Wk, const float* __restrict__ bk,
    const float* __restrict__ Wv, const float* __restrict__ bv,
    float* __restrict__ out)
{
    __shared__ short xb[PP * XB_STRIDE];   // 4864 B; reused as attn weights (4096 B) later
    __shared__ short qkv[TT * PS];         // 67712 B

    const int tid  = threadIdx.x;
    const int wave = tid >> 6;      // 0..7
    const int lane = tid & 63;
    const int quad = lane >> 4;
    const int l16  = lane & 15;

    const int blk = blockIdx.x;
    const int b   = blk / (HWp / PP);
    const int p0  = (blk % (HWp / PP)) * PP;

    // ---- Preload weight A-fragments + biases into registers ----
    // Stacked f rows: [0,64)=Wq, [64,128)=Wk, [128,256)=Wv. Wave w owns f-tiles 2w,2w+1.
    // A-frag (16x16x32): A[m = lane&15][k = quad*8 + j], k = channel c.
    short8 wfrag[2][4];
    float  bias[2][4];
#pragma unroll
    for (int i = 0; i < 2; ++i) {
        const int f0  = (wave * 2 + i) * 16;
        const int row = f0 + l16;
        const float* wrow;
        if (row < DD)            wrow = Wq + row * CC;
        else if (row < 2 * DD)   wrow = Wk + (row - DD) * CC;
        else                     wrow = Wv + (row - 2 * DD) * CC;
#pragma unroll
        for (int kc = 0; kc < 4; ++kc) {
            const float* src = wrow + kc * 32 + quad * 8;
            short8 v;
#pragma unroll
            for (int j = 0; j < 8; ++j) v[j] = f2bf(src[j]);
            wfrag[i][kc] = v;
        }
        const int fb = f0 + quad * 4;
        const float* bsrc; int off;
        if (fb < DD)            { bsrc = bq; off = fb; }
        else if (fb < 2 * DD)   { bsrc = bk; off = fb - DD; }
        else                    { bsrc = bv; off = fb - 2 * DD; }
#pragma unroll
        for (int r = 0; r < 4; ++r) bias[i][r] = bsrc[off + r];
    }

    // ---- Projection: per t, stage x tile (bf16) -> LDS, MFMA -> qkv LDS ----
    const int c0 = tid >> 2;            // 0..127
    const int p4 = (tid & 3) * 4;       // 0,4,8,12
    const float* xsrc0 = x + ((size_t)(b * TT) * CC + c0) * HWp + p0 + p4;

    float4 cur = *(const float4*)xsrc0;
    for (int t = 0; t < TT; ++t) {
        float4 nxt = cur;
        if (t < TT - 1)
            nxt = *(const float4*)(xsrc0 + (size_t)(t + 1) * CC * HWp);  // in flight across this iter

        __syncthreads();   // xb from previous iteration fully consumed
        xb[(p4 + 0) * XB_STRIDE + c0] = f2bf(cur.x);
        xb[(p4 + 1) * XB_STRIDE + c0] = f2bf(cur.y);
        xb[(p4 + 2) * XB_STRIDE + c0] = f2bf(cur.z);
        xb[(p4 + 3) * XB_STRIDE + c0] = f2bf(cur.w);
        __syncthreads();

        floatx4 acc[2];
#pragma unroll
        for (int i = 0; i < 2; ++i)
#pragma unroll
            for (int r = 0; r < 4; ++r) acc[i][r] = 0.f;
#pragma unroll
        for (int kc = 0; kc < 4; ++kc) {
            short8 xf = *(const short8*)&xb[l16 * XB_STRIDE + kc * 32 + quad * 8];
            acc[0] = __builtin_amdgcn_mfma_f32_16x16x32_bf16(wfrag[0][kc], xf, acc[0], 0, 0, 0);
            acc[1] = __builtin_amdgcn_mfma_f32_16x16x32_bf16(wfrag[1][kc], xf, acc[1], 0, 0, 0);
        }
        // D layout: col(n=p) = lane&15, row(m=f) = quad*4 + r.
#pragma unroll
        for (int i = 0; i < 2; ++i) {
            const int f0 = (wave * 2 + i) * 16 + quad * 4;
            short4v o;
#pragma unroll
            for (int r = 0; r < 4; ++r) o[r] = f2bf(acc[i][r] + bias[i][r]);
            *(short4v*)&qkv[t * PS + l16 * QKV_STRIDE + f0] = o;
        }
        cur = nxt;
    }
    __syncthreads();   // qkv complete; xb dead -> reuse as attn weights

    float* attn = (float*)xb;   // attn[(tq*PP + p)*8 + s], 4096 B

    // ---- Scores + softmax: wave = tq; lanes = p(16) x dq(4), D split 16-wide ----
    {
        const int p  = l16;
        const int dq = quad;     // d-slice [dq*16, dq*16+16)
        const int tq = wave;

        const short* qp = &qkv[tq * PS + p * QKV_STRIDE + dq * 16];
        float qv[16];
        {
            short8 q0 = *(const short8*)qp;
            short8 q1 = *(const short8*)(qp + 8);
#pragma unroll
            for (int j = 0; j < 8; ++j) { qv[j] = bf2f(q0[j]); qv[8 + j] = bf2f(q1[j]); }
        }
        float sc[TT];
#pragma unroll
        for (int s = 0; s < TT; ++s) {
            const short* kp = &qkv[s * PS + p * QKV_STRIDE + DD + dq * 16];
            short8 k0 = *(const short8*)kp;
            short8 k1 = *(const short8*)(kp + 8);
            float a = 0.f;
#pragma unroll
            for (int j = 0; j < 8; ++j) a += qv[j] * bf2f(k0[j]);
#pragma unroll
            for (int j = 0; j < 8; ++j) a += qv[8 + j] * bf2f(k1[j]);
            sc[s] = a;
        }
        // butterfly over dq (lane bits 4,5); p preserved
#pragma unroll
        for (int s = 0; s < TT; ++s) {
            sc[s] += __shfl_xor(sc[s], 16);
            sc[s] += __shfl_xor(sc[s], 32);
            sc[s] *= 0.125f;    // 1/sqrt(64)
        }
        float m = sc[0];
#pragma unroll
        for (int s = 1; s < TT; ++s) m = fmaxf(m, sc[s]);
        float sum = 0.f;
#pragma unroll
        for (int s = 0; s < TT; ++s) { sc[s] = __expf(sc[s] - m); sum += sc[s]; }
        const float inv = 1.f / sum;
        if (dq == 0) {
            float* ap = &attn[(tq * PP + p) * 8];
#pragma unroll
            for (int s = 0; s < TT; ++s) ap[s] = sc[s] * inv;
        }
    }
    __syncthreads();

    // ---- PV: wave = tq; lanes = p(16) x eq(4), e split 32-wide ----
    {
        const int p  = l16;
        const int eq = quad;
        const int tq = wave;

        float w[TT];
        {
            const float4 wa = *(const float4*)&attn[(tq * PP + p) * 8];
            const float4 wb = *(const float4*)&attn[(tq * PP + p) * 8 + 4];
            w[0]=wa.x; w[1]=wa.y; w[2]=wa.z; w[3]=wa.w;
            w[4]=wb.x; w[5]=wb.y; w[6]=wb.z; w[7]=wb.w;
        }
        float2v o2[16];
#pragma unroll
        for (int k = 0; k < 16; ++k) { o2[k][0] = 0.f; o2[k][1] = 0.f; }
#pragma unroll
        for (int s = 0; s < TT; ++s) {
            const short* vp = &qkv[s * PS + p * QKV_STRIDE + 2 * DD + eq * 32];
            const float a = w[s];
            const float2v a2 = { a, a };
#pragma unroll
            for (int c = 0; c < 4; ++c) {
                short8 v = *(const short8*)(vp + c * 8);
#pragma unroll
                for (int j = 0; j < 4; ++j) {
                    float2v f = { bf2f(v[2 * j]), bf2f(v[2 * j + 1]) };
                    o2[c * 4 + j] += a2 * f;   // v_pk_fma_f32 hoped
                }
            }
        }
        // out[b][tq][e][h][w]; lanes 0..15 = consecutive pixels -> 64B segments
        float* op = out + ((size_t)((b * TT + tq) * CC + eq * 32)) * HWp + p0 + p;
#pragma unroll
        for (int k = 0; k < 16; ++k) {
            op[(size_t)(2 * k) * HWp]     = o2[k][0];
            op[(size_t)(2 * k + 1) * HWp] = o2[k][1];
        }
    }
}

extern "C" void kernel_launch(void* const* d_in, const int* in_sizes, int n_in,
                              void* d_out, int out_size, void* d_ws, size_t ws_size,
                              hipStream_t stream) {
    const float* x  = (const float*)d_in[0];
    const float* Wq = (const float*)d_in[1];
    const float* bq = (const float*)d_in[2];
    const float* Wk = (const float*)d_in[3];
    const float* bk = (const float*)d_in[4];
    const float* Wv = (const float*)d_in[5];
    const float* bv = (const float*)d_in[6];
    float* out = (float*)d_out;

    const int blocks = 4 * (HWp / PP);   // B=4 x 576 pixel-tiles = 2304
    ta_kernel<<<blocks, 512, 0, stream>>>(x, Wq, bq, Wk, bk, Wv, bv, out);
}